// Round 14
// baseline (527.709 us; speedup 1.0000x reference)
//
#include <hip/hip_runtime.h>
#include <hip/hip_fp16.h>

// GCN: out = Ahat*(relu(Ahat*(x@W1)+b1))@W2 + b2,  Ahat = D^-1/2 (A+I) D^-1/2
// N=100000, E=1600000, IN=256, HID=128, OUT=64, fp32 in/out.
// R20: XCD-sliced agg, structure-corrected. Evidence chain:
//   - agg1 invariant across R6/R7/R17: L2-fill (TCC FETCH) ~2.9TB/s on 188MB
//     -> L3->L2 path is the binder (R7 falsified issue-count theory).
//   - R8 verified bid%8->XCD slicing cuts FETCH 190->43MB, but 1-node/wave
//     x8 cgs paid the per-edge loop 8x redundantly -> 4x slower.
//   - Fix: 8 nodes/WAVE (one per 8-lane stream). One wave-instr covers 8
//     edges (one/stream) -> per-edge instr cost ~= R6 even at 8 cgs.
//     4-deep csr unroll = 32 gathers in flight/wave. csr loads NT (don't
//     evict the 3.2MB h-slice from the 4MB XCD L2).
//   - h1 blocked [8][N][16] (R8-verified BLOCKED gemm epilogue); agg2 on
//     h2 blocked [4][N][16] (slice on 2 XCDs). All else frozen from R17
//     (400.3us best: stage_bk scatter, NT agg outputs, dinv fold).

#define IN_DIM 256
#define HID_DIM 128
#define OUT_DIM 64
#define BSHIFT 7
#define MAXNB 1024      // supports N <= 131072
#define STAGE_CAP 8192  // max edges staged per scatter block (32 KB LDS)

typedef _Float16 half8 __attribute__((ext_vector_type(8)));
typedef _Float16 h2v __attribute__((ext_vector_type(2)));
typedef float floatx4 __attribute__((ext_vector_type(4)));
typedef float f2v __attribute__((ext_vector_type(2)));

// ---- build A: bucket histogram (LDS-privatized) + W^T fp16 conversion ----
__global__ __launch_bounds__(256) void bucket_hist(const int* __restrict__ dst, int E,
                                                   int NB, int* __restrict__ bcnt,
                                                   const float* __restrict__ W1,
                                                   const float* __restrict__ W2,
                                                   __half* __restrict__ Wt1,
                                                   __half* __restrict__ Wt2) {
  __shared__ int h[MAXNB];
  int t = threadIdx.x;
  int gid = blockIdx.x * 256 + t, gsz = gridDim.x * 256;
  for (int i = gid; i < IN_DIM * HID_DIM; i += gsz) {
    int n = i / IN_DIM, k = i % IN_DIM;
    Wt1[i] = __float2half(W1[k * HID_DIM + n]);
  }
  for (int i = gid; i < HID_DIM * OUT_DIM; i += gsz) {
    int n = i / HID_DIM, k = i % HID_DIM;
    Wt2[i] = __float2half(W2[k * OUT_DIM + n]);
  }
  for (int i = t; i < MAXNB; i += 256) h[i] = 0;
  __syncthreads();
  for (int i = gid; i < E; i += gsz) atomicAdd(&h[dst[i] >> BSHIFT], 1);
  __syncthreads();
  for (int i = t; i < NB; i += 256) {
    int v = h[i];
    if (v) atomicAdd(&bcnt[i], v);
  }
}

// ---- build B: scan bucket counts; init global cursors; off[N]=E ----
__global__ __launch_bounds__(1024) void bucket_scan(const int* __restrict__ bcnt, int NB,
                                                    int E, int* __restrict__ boff,
                                                    int* __restrict__ bcur,
                                                    int* __restrict__ off, int N) {
  __shared__ int sh[1024];
  int t = threadIdx.x;
  int v = (t < NB) ? bcnt[t] : 0;
  sh[t] = v;
  __syncthreads();
  for (int s = 1; s < 1024; s <<= 1) {
    int a = (t >= s) ? sh[t - s] : 0;
    __syncthreads();
    sh[t] += a;
    __syncthreads();
  }
  if (t < NB) {
    int ex = sh[t] - v;
    boff[t] = ex;
    bcur[t] = ex;
  }
  if (t == 0) {
    boff[NB] = E;
    off[N] = E;
  }
}

// ---- build C: LDS-staged counting sort of each chunk, coalesced writeout ----
// pairs[g] = (src<<7)|(dst&127), bucket-contiguous.
__global__ __launch_bounds__(256) void bucket_scatter(const int* __restrict__ src,
                                                      const int* __restrict__ dst, int E,
                                                      int NB, int* __restrict__ bcur,
                                                      int* __restrict__ pairs) {
  __shared__ int hist[MAXNB];
  __shared__ int base_l[MAXNB];
  __shared__ int base_g[MAXNB];
  __shared__ int cur[MAXNB];
  __shared__ int sm[256];
  __shared__ int stage[STAGE_CAP];
  __shared__ unsigned short stage_bk[STAGE_CAP];
  int t = threadIdx.x;
  int chunk = (E + gridDim.x - 1) / gridDim.x;
  int s0 = blockIdx.x * chunk, s1 = min(E, s0 + chunk);
  int cnt = s1 - s0;

  for (int i = t; i < MAXNB; i += 256) hist[i] = 0;
  __syncthreads();
  for (int i = s0 + t; i < s1; i += 256) atomicAdd(&hist[dst[i] >> BSHIFT], 1);
  __syncthreads();
  {
    int i0 = t * 4;
    int v0 = hist[i0], v1 = hist[i0 + 1], v2 = hist[i0 + 2], v3 = hist[i0 + 3];
    int s = v0 + v1 + v2 + v3;
    sm[t] = s;
    __syncthreads();
    for (int st = 1; st < 256; st <<= 1) {
      int a = (t >= st) ? sm[t - st] : 0;
      __syncthreads();
      sm[t] += a;
      __syncthreads();
    }
    int ex = sm[t] - s;
    base_l[i0] = ex;
    base_l[i0 + 1] = ex + v0;
    base_l[i0 + 2] = ex + v0 + v1;
    base_l[i0 + 3] = ex + v0 + v1 + v2;
    cur[i0] = ex;
    cur[i0 + 1] = ex + v0;
    cur[i0 + 2] = ex + v0 + v1;
    cur[i0 + 3] = ex + v0 + v1 + v2;
    if (v0) base_g[i0] = atomicAdd(&bcur[i0], v0);
    if (v1) base_g[i0 + 1] = atomicAdd(&bcur[i0 + 1], v1);
    if (v2) base_g[i0 + 2] = atomicAdd(&bcur[i0 + 2], v2);
    if (v3) base_g[i0 + 3] = atomicAdd(&bcur[i0 + 3], v3);
  }
  __syncthreads();
  for (int i = s0 + t; i < s1; i += 256) {
    int d = dst[i];
    int bk = d >> BSHIFT;
    int r = atomicAdd(&cur[bk], 1);
    stage[r] = (src[i] << BSHIFT) | (d & ((1 << BSHIFT) - 1));
    stage_bk[r] = (unsigned short)bk;
  }
  __syncthreads();
  for (int j = t; j < cnt; j += 256) {
    int bk = stage_bk[j];
    pairs[base_g[bk] + (j - base_l[bk])] = stage[j];
  }
}

// ---- build D: per-bucket counting sort -> csr/off/dinv ----
__global__ __launch_bounds__(256) void bucket_csr(const int* __restrict__ pairs,
                                                  const int* __restrict__ boff, int N,
                                                  int* __restrict__ csr,
                                                  int* __restrict__ off,
                                                  float* __restrict__ dinv) {
  int b = blockIdx.x;
  int t = threadIdx.x;
  int n0 = b << BSHIFT;
  int cnt = min(128, N - n0);
  __shared__ int ldeg[128], sh[128], lcur[128];
  if (t < 128) ldeg[t] = 0;
  __syncthreads();
  int e0 = boff[b], e1 = boff[b + 1];
  for (int e = e0 + t; e < e1; e += 256) atomicAdd(&ldeg[pairs[e] & 127], 1);
  __syncthreads();
  int v = (t < 128) ? ldeg[t] : 0;
  if (t < 128) sh[t] = v;
  __syncthreads();
  for (int s = 1; s < 128; s <<= 1) {
    int a = (t < 128 && t >= s) ? sh[t - s] : 0;
    __syncthreads();
    if (t < 128) sh[t] += a;
    __syncthreads();
  }
  if (t < cnt) {
    int ex = sh[t] - v;
    off[n0 + t] = e0 + ex;
    dinv[n0 + t] = 1.0f / sqrtf((float)(v + 1));
    lcur[t] = ex;
  }
  __syncthreads();
  for (int e = e0 + t; e < e1; e += 256) {
    int pk = pairs[e];
    int r = atomicAdd(&lcur[pk & 127], 1);
    csr[e0 + r] = pk >> BSHIFT;
  }
}

// C[M x NC](fp16) = A[M x K] @ W[K x NC] via v_mfma_f32_16x16x32_f16.
// SCALE: multiply output row by rowscale[row] (dinv fold for layer 1).
// BLOCKED: write C column-blocked [NC/16][M][16] (for XCD-sliced agg).
template <int K, int NC, typename AT, bool SCALE, bool BLOCKED>
__global__ __launch_bounds__(256) void mfma_gemm(const AT* __restrict__ A,
                                                 const __half* __restrict__ Wt,
                                                 __half* __restrict__ C, int M,
                                                 const float* __restrict__ rowscale) {
  constexpr int BK = 32;
  constexpr int STR = BK + 8;
  constexpr int CT = NC / 16;
  __shared__ _Float16 As[128 * STR];
  __shared__ _Float16 Ws[NC * STR];
  int row0 = blockIdx.x * 128;
  int t = threadIdx.x;
  int wave = t >> 6, lane = t & 63, quad = lane >> 4, lr = lane & 15;
  floatx4 acc[2][CT] = {};
  int arow = t >> 1, ako = (t & 1) * 16;
  int grow = row0 + arow;

  for (int k0 = 0; k0 < K; k0 += BK) {
    {
      half8 h0 = {}, h1 = {};
      if (grow < M) {
        if constexpr (sizeof(AT) == 4) {
          const float4* ap = (const float4*)(A + (size_t)grow * K + k0 + ako);
          float4 v0 = ap[0], v1 = ap[1], v2 = ap[2], v3 = ap[3];
          h0[0] = (_Float16)v0.x; h0[1] = (_Float16)v0.y;
          h0[2] = (_Float16)v0.z; h0[3] = (_Float16)v0.w;
          h0[4] = (_Float16)v1.x; h0[5] = (_Float16)v1.y;
          h0[6] = (_Float16)v1.z; h0[7] = (_Float16)v1.w;
          h1[0] = (_Float16)v2.x; h1[1] = (_Float16)v2.y;
          h1[2] = (_Float16)v2.z; h1[3] = (_Float16)v2.w;
          h1[4] = (_Float16)v3.x; h1[5] = (_Float16)v3.y;
          h1[6] = (_Float16)v3.z; h1[7] = (_Float16)v3.w;
        } else {
          const half8* ap = (const half8*)(A + (size_t)grow * K + k0 + ako);
          h0 = ap[0];
          h1 = ap[1];
        }
      }
      *(half8*)&As[arow * STR + ako] = h0;
      *(half8*)&As[arow * STR + ako + 8] = h1;
    }
    if constexpr (NC == 128) {
      int r = t >> 1, ko = (t & 1) * 16;
      const half8* wp = (const half8*)(Wt + (size_t)r * K + k0 + ko);
      *(half8*)&Ws[r * STR + ko] = wp[0];
      *(half8*)&Ws[r * STR + ko + 8] = wp[1];
    } else {  // NC == 64
      int r = t >> 2, ko = (t & 3) * 8;
      *(half8*)&Ws[r * STR + ko] = *(const half8*)(Wt + (size_t)r * K + k0 + ko);
    }
    __syncthreads();
    {
      int a_off = (wave * 32 + lr) * STR + quad * 8;
      half8 a0 = *(const half8*)&As[a_off];
      half8 a1 = *(const half8*)&As[a_off + 16 * STR];
      int b_off = lr * STR + quad * 8;
#pragma unroll
      for (int ct = 0; ct < CT; ct++) {
        half8 bfr = *(const half8*)&Ws[b_off + ct * 16 * STR];
        acc[0][ct] = __builtin_amdgcn_mfma_f32_16x16x32_f16(a0, bfr, acc[0][ct], 0, 0, 0);
        acc[1][ct] = __builtin_amdgcn_mfma_f32_16x16x32_f16(a1, bfr, acc[1][ct], 0, 0, 0);
      }
    }
    __syncthreads();
  }
#pragma unroll
  for (int rt = 0; rt < 2; rt++) {
    int rbase = row0 + wave * 32 + rt * 16 + quad * 4;
#pragma unroll
    for (int i = 0; i < 4; i++) {
      int row = rbase + i;
      if (row < M) {
        float sc = 1.f;
        if constexpr (SCALE) sc = rowscale[row];
#pragma unroll
        for (int ct = 0; ct < CT; ct++) {
          size_t idx;
          if constexpr (BLOCKED) idx = (size_t)ct * M * 16 + (size_t)row * 16 + lr;
          else                   idx = (size_t)row * NC + ct * 16 + lr;
          C[idx] = __float2half(acc[rt][ct][i] * sc);
        }
      }
    }
  }
}

// agg layer 1 (XCD-sliced): h blocked [8][N][16]; cg = bid&7 -> one XCD's L2
// holds the 3.2MB slice. Wave = 8 nodes (one per 8-lane stream); each stream
// walks its node's csr serially (4-deep NT unroll -> 32 gathers in flight).
// One wave-instr covers 8 edges -> per-edge cost ~= R6 despite 8 cgs.
// Rows pre-scaled by dinv; out row-major NT (carries di*relu(.)*di fold).
__global__ __launch_bounds__(256) void agg1_kernel(const __half* __restrict__ h,
                                                   const int* __restrict__ off,
                                                   const int* __restrict__ csr,
                                                   const float* __restrict__ dinv,
                                                   const float* __restrict__ bias,
                                                   __half* __restrict__ out, int N) {
  int cg = blockIdx.x & 7;
  int nb = (blockIdx.x >> 3) * 32;
  int t = threadIdx.x;
  int wave = t >> 6, lane = t & 63;
  int st = lane >> 3, l8 = lane & 7;
  int n = nb + wave * 8 + st;
  if (n >= N) return;  // no barriers below -> safe
  const _Float16* __restrict__ hp =
      (const _Float16*)h + (size_t)cg * N * 16 + l8 * 2;
  float a0 = 0.f, a1 = 0.f;
  auto gacc = [&](int s) {
    h2v v = *(const h2v*)(hp + (size_t)s * 16);
    a0 += (float)v[0];
    a1 += (float)v[1];
  };
  gacc(n);  // self-loop (pre-scaled row)
  int e = off[n], e1 = off[n + 1];
  for (; e + 4 <= e1; e += 4) {
    int s0 = __builtin_nontemporal_load(csr + e);
    int s1 = __builtin_nontemporal_load(csr + e + 1);
    int s2 = __builtin_nontemporal_load(csr + e + 2);
    int s3 = __builtin_nontemporal_load(csr + e + 3);
    gacc(s0); gacc(s1); gacc(s2); gacc(s3);
  }
  for (; e < e1; e++) gacc(__builtin_nontemporal_load(csr + e));
  float di = dinv[n];
  int c = cg * 16 + l8 * 2;
  float r0 = fmaxf(di * a0 + bias[c], 0.f) * di;      // trailing *di = L2 fold
  float r1 = fmaxf(di * a1 + bias[c + 1], 0.f) * di;
  __half2 hv = __floats2half2_rn(r0, r1);
  unsigned int bits;
  __builtin_memcpy(&bits, &hv, 4);
  __builtin_nontemporal_store(
      bits, (unsigned int*)((_Float16*)out + (size_t)n * HID_DIM + c));
}

// agg layer 2 (sliced): h blocked [4][N][16]; cg = bid&3 (slice on 2 XCDs).
// Same 8-node/wave structure; fp32 NT output, bias only (rows pre-scaled).
__global__ __launch_bounds__(256) void agg2_kernel(const __half* __restrict__ h,
                                                   const int* __restrict__ off,
                                                   const int* __restrict__ csr,
                                                   const float* __restrict__ dinv,
                                                   const float* __restrict__ bias,
                                                   float* __restrict__ out, int N) {
  int cg = blockIdx.x & 3;
  int nb = (blockIdx.x >> 2) * 32;
  int t = threadIdx.x;
  int wave = t >> 6, lane = t & 63;
  int st = lane >> 3, l8 = lane & 7;
  int n = nb + wave * 8 + st;
  if (n >= N) return;
  const _Float16* __restrict__ hp =
      (const _Float16*)h + (size_t)cg * N * 16 + l8 * 2;
  float a0 = 0.f, a1 = 0.f;
  auto gacc = [&](int s) {
    h2v v = *(const h2v*)(hp + (size_t)s * 16);
    a0 += (float)v[0];
    a1 += (float)v[1];
  };
  gacc(n);  // self-loop
  int e = off[n], e1 = off[n + 1];
  for (; e + 4 <= e1; e += 4) {
    int s0 = __builtin_nontemporal_load(csr + e);
    int s1 = __builtin_nontemporal_load(csr + e + 1);
    int s2 = __builtin_nontemporal_load(csr + e + 2);
    int s3 = __builtin_nontemporal_load(csr + e + 3);
    gacc(s0); gacc(s1); gacc(s2); gacc(s3);
  }
  for (; e < e1; e++) gacc(__builtin_nontemporal_load(csr + e));
  float di = dinv[n];
  int c = cg * 16 + l8 * 2;
  f2v o;
  o[0] = di * a0 + bias[c];
  o[1] = di * a1 + bias[c + 1];
  __builtin_nontemporal_store(o, (f2v*)(out + (size_t)n * OUT_DIM + c));
}

extern "C" void kernel_launch(void* const* d_in, const int* in_sizes, int n_in,
                              void* d_out, int out_size, void* d_ws, size_t ws_size,
                              hipStream_t stream) {
  const float* x  = (const float*)d_in[0];
  const int*   ei = (const int*)d_in[1];
  const float* W1 = (const float*)d_in[2];
  const float* b1 = (const float*)d_in[3];
  const float* W2 = (const float*)d_in[4];
  const float* b2 = (const float*)d_in[5];
  float* out = (float*)d_out;

  int N = in_sizes[0] / IN_DIM;
  int E = in_sizes[1] / 2;
  const int* src = ei;
  const int* dst = ei + E;
  int NB = (N + 127) >> BSHIFT;  // 782 for N=100000 (<= MAXNB)

  char* p = (char*)d_ws;
  auto alloc = [&](size_t bytes) {
    char* q = p;
    p += (bytes + 255) & ~(size_t)255;
    return q;
  };
  int*    bcnt  = (int*)alloc((size_t)NB * 4);
  int*    boff  = (int*)alloc((size_t)(NB + 1) * 4);
  int*    bcur  = (int*)alloc((size_t)NB * 4);
  int*    pairs = (int*)alloc((size_t)E * 4);   // packed (src<<7)|(dst&127)
  int*    csr   = (int*)alloc((size_t)E * 4);
  int*    off   = (int*)alloc((size_t)(N + 1) * 4);
  float*  dinv  = (float*)alloc((size_t)N * 4);
  __half* h1    = (__half*)alloc((size_t)N * HID_DIM * 2);  // blocked [8][N][16]
  __half* z16   = (__half*)alloc((size_t)N * HID_DIM * 2);  // row-major
  __half* Wt1   = (__half*)alloc((size_t)IN_DIM * HID_DIM * 2);
  __half* Wt2   = (__half*)alloc((size_t)HID_DIM * OUT_DIM * 2);
  __half* h2    = h1;  // reused, blocked [4][N][16]
  (void)ws_size; (void)n_in; (void)out_size;

  hipMemsetAsync(bcnt, 0, (size_t)NB * 4, stream);

  bucket_hist<<<1024, 256, 0, stream>>>(dst, E, NB, bcnt, W1, W2, Wt1, Wt2);
  bucket_scan<<<1, 1024, 0, stream>>>(bcnt, NB, E, boff, bcur, off, N);
  int sblk = max(256, (E + STAGE_CAP - 1) / STAGE_CAP);  // 256 blocks, chunk 6250
  bucket_scatter<<<sblk, 256, 0, stream>>>(src, dst, E, NB, bcur, pairs);
  bucket_csr<<<NB, 256, 0, stream>>>(pairs, boff, N, csr, off, dinv);

  int gb = (N + 127) / 128;
  int nwb = (N + 31) / 32;  // node batches of 32 (8 nodes x 4 waves)
  // layer 1: h1 rows pre-scaled by dinv, blocked [8][N][16]
  mfma_gemm<IN_DIM, HID_DIM, float, true, true>
      <<<gb, 256, 0, stream>>>(x, Wt1, h1, N, dinv);
  agg1_kernel<<<8 * nwb, 256, 0, stream>>>(h1, off, csr, dinv, b1, z16, N);

  // layer 2: z16 carries the dinv row-scale; h2 blocked [4][N][16]
  mfma_gemm<HID_DIM, OUT_DIM, __half, false, true>
      <<<gb, 256, 0, stream>>>(z16, Wt2, h2, N, nullptr);
  agg2_kernel<<<4 * nwb, 256, 0, stream>>>(h2, off, csr, dinv, b2, out, N);
}